// Round 3
// baseline (499.185 us; speedup 1.0000x reference)
//
#include <hip/hip_runtime.h>
#include <stdint.h>

#define KPS 512
#define NBOX 1536
#define NBINS 4096

// scale cell counts: 32*H*H*3
#define S13 16224
#define S26 64896
#define S52 259584
#define TOTCELL 340704

// candidate segment bases/caps (in keys)
#define C13_BASE 0
#define C26_BASE 16384
#define C52_BASE 81920
#define CAND_CAP 344064

__device__ __forceinline__ uint32_t f2u(float x){ union{float f;uint32_t u;}v; v.f=x; return v.u; }
__device__ __forceinline__ float u2f(uint32_t x){ union{float f;uint32_t u;}v; v.u=x; return v.f; }

__device__ __forceinline__ int binOf(float s){
    int b = (int)((s - 0.6f) * 10240.0f);
    if (b < 0) b = 0;
    if (b > NBINS-1) b = NBINS-1;
    return b;
}

// counters: [0..2] candCnt, [3..5] abovePos, [6..8] stashCnt, [9..11] cutoffB, [12..14] aboveCount
__global__ void k_init(int* hist, int* cnt){
    int id = blockIdx.x*256 + threadIdx.x;
    if (id < 3*NBINS) hist[id] = 0;
    if (id < 32) cnt[id] = 0;
}

__global__ void k_score(const float* __restrict__ o13, const float* __restrict__ o26,
                        const float* __restrict__ o52,
                        unsigned long long* __restrict__ cand, int* __restrict__ cnt,
                        int* __restrict__ hist){
    int id = blockIdx.x*256 + threadIdx.x;
    bool live = (id < TOTCELL);
    int scale=0, idl=0, H=13, segbase=0;
    const float* src = o13;
    if (live){
        if (id < S13)            { scale=0; idl=id;            H=13; src=o13; segbase=C13_BASE; }
        else if (id < S13+S26)   { scale=1; idl=id-S13;        H=26; src=o26; segbase=C26_BASE; }
        else                     { scale=2; idl=id-(S13+S26);  H=52; src=o52; segbase=C52_BASE; }
    }
    int HW = H*H;
    // plane-major thread mapping for coalescing: idl = p*HW + hw, p = n*3 + a
    int p  = idl / HW;
    int hw = idl - p*HW;
    int n  = p / 3;
    int a  = p - n*3;
    int cidx = (n*HW + hw)*3 + a;       // reference flat cell index
    float s = 0.f;
    if (live){
        float x = src[(size_t)(n*255 + a*85)*HW + hw];
        s = (float)(1.0 / (1.0 + exp(-(double)x)));   // correctly-rounded f32 sigmoid
    }
    bool pred = live && (s > 0.6f);
    int lane = threadIdx.x & 63;
    unsigned long long lanebit_m1 = (lane == 63) ? ~0ull >> 1 : ((1ull << lane) - 1ull);
    // wave-aggregated compaction per scale (waves can straddle scale boundaries)
    #pragma unroll
    for (int sc = 0; sc < 3; sc++){
        unsigned long long m = __ballot(pred && scale == sc);
        if (m){
            int leader = __ffsll((long long)m) - 1;
            int base = 0;
            if (lane == leader) base = atomicAdd(&cnt[sc], __popcll(m));
            base = __shfl(base, leader);
            if (pred && scale == sc){
                int pos = base + __popcll(m & lanebit_m1);
                unsigned long long key = ((unsigned long long)f2u(s) << 20)
                                       | ((unsigned long long)(2-scale) << 18)
                                       | (unsigned long long)(262143 - cidx);
                cand[segbase + pos] = key;
            }
        }
    }
    if (pred) atomicAdd(&hist[scale*NBINS + binOf(s)], 1);
}

__global__ void __launch_bounds__(1024) k_cutoff(const int* __restrict__ hist, int* __restrict__ cnt){
    int s = blockIdx.x, t = threadIdx.x;
    __shared__ int h[NBINS];
    __shared__ int suf[1024];
    #pragma unroll
    for (int k=0;k<4;k++) h[t*4+k] = hist[s*NBINS + t*4 + k];
    __syncthreads();
    int part = h[4*t] + h[4*t+1] + h[4*t+2] + h[4*t+3];
    suf[t] = part; __syncthreads();
    for (int d=1; d<1024; d<<=1){
        int v = (t+d < 1024) ? suf[t+d] : 0;
        __syncthreads();
        suf[t] += v;
        __syncthreads();
    }
    int total = suf[0];
    int A = (t < 1023) ? suf[t+1] : 0;
    int ca3 = A;
    int ca2 = A   + h[4*t+3];
    int ca1 = ca2 + h[4*t+2];
    int ca0 = ca1 + h[4*t+1];
    int ca[4] = {ca0, ca1, ca2, ca3};
    if (t == 0 && total < KPS){ cnt[9+s] = -1; cnt[12+s] = total; }
    #pragma unroll
    for (int k=0;k<4;k++){
        int b = 4*t + k;
        if (ca[k] < KPS && ca[k] + h[b] >= KPS){ cnt[9+s] = b; cnt[12+s] = ca[k]; }
    }
}

__global__ void k_classify(const unsigned long long* __restrict__ cand, int* __restrict__ cnt,
                           unsigned long long* __restrict__ sel, unsigned long long* __restrict__ stash){
    int id = blockIdx.x*256 + threadIdx.x;
    int scale, segbase;
    if (id < C26_BASE)      { scale=0; segbase=C13_BASE; }
    else if (id < C52_BASE) { scale=1; segbase=C26_BASE; }
    else                    { scale=2; segbase=C52_BASE; }
    int slot = id - segbase;
    bool live = (id < CAND_CAP) && (slot < cnt[scale]);
    unsigned long long key = live ? cand[id] : 0ull;
    int B = cnt[9+scale];
    int bin = live ? binOf(u2f((uint32_t)(key >> 20))) : -2;
    int lane = threadIdx.x & 63;
    unsigned long long lanebit_m1 = (lane == 63) ? ~0ull >> 1 : ((1ull << lane) - 1ull);
    bool above = live && (bin > B);
    bool bound = live && (bin == B);
    // wave-aggregate both counters (waves may straddle scales; loop scales)
    #pragma unroll
    for (int sc = 0; sc < 3; sc++){
        unsigned long long ma = __ballot(above && scale == sc);
        if (ma){
            int leader = __ffsll((long long)ma) - 1;
            int base = 0;
            if (lane == leader) base = atomicAdd(&cnt[3+sc], __popcll(ma));
            base = __shfl(base, leader);
            if (above && scale == sc)
                sel[sc*KPS + base + __popcll(ma & lanebit_m1)] = key;
        }
        unsigned long long mb = __ballot(bound && scale == sc);
        if (mb){
            int leader = __ffsll((long long)mb) - 1;
            int base = 0;
            if (lane == leader) base = atomicAdd(&cnt[6+sc], __popcll(mb));
            base = __shfl(base, leader);
            if (bound && scale == sc){
                int q = base + __popcll(mb & lanebit_m1);
                if (q < 1024) stash[sc*1024 + q] = key;
            }
        }
    }
}

__global__ void __launch_bounds__(1024) k_finalize(const int* __restrict__ cnt,
                           unsigned long long* __restrict__ sel, const unsigned long long* __restrict__ stash){
    int s = blockIdx.x, t = threadIdx.x;
    __shared__ unsigned long long sk[1024];
    int sc = cnt[6+s]; if (sc > 1024) sc = 1024;
    sk[t] = (t < sc) ? stash[s*1024 + t] : 0ull;
    __syncthreads();
    for (int k=2; k<=1024; k<<=1)
        for (int j=k>>1; j>0; j>>=1){
            int ixj = t ^ j;
            if (ixj > t){
                bool up = ((t & k) == 0);   // descending overall
                unsigned long long a = sk[t], b = sk[ixj];
                if (up ? (a < b) : (a > b)){ sk[t] = b; sk[ixj] = a; }
            }
            __syncthreads();
        }
    int above = cnt[12+s];
    int need = KPS - above; if (need < 0) need = 0;
    int m = (need < sc) ? need : sc;
    if (t < m) sel[s*KPS + above + t] = sk[t];
    if (t >= above + m && t < KPS) sel[s*KPS + t] = 0ull;   // sentinels
}

__global__ void k_decode(const float* __restrict__ o13, const float* __restrict__ o26,
                         const float* __restrict__ o52,
                         const float* __restrict__ a13, const float* __restrict__ a26,
                         const float* __restrict__ a52,
                         const unsigned long long* __restrict__ sel, float* __restrict__ boxes){
    int gtid = blockIdx.x*256 + threadIdx.x;
    int b = gtid >> 6;
    int lane = threadIdx.x & 63;
    if (b >= NBOX) return;
    unsigned long long key = sel[b];
    float* row = boxes + b*12;
    if ((key >> 20) == 0ull){           // sentinel
        if (lane < 9) row[lane] = 0.f;
        return;
    }
    int scale = 2 - (int)((key >> 18) & 3ull);
    int cidx  = 262143 - (int)(key & 0x3FFFFull);
    uint32_t sbits = (uint32_t)(key >> 20);
    const float* src; const float* anch; int H; float tt;
    if (scale == 0){ src=o13; anch=a13; H=13; tt=32.f; }
    else if (scale == 1){ src=o26; anch=a26; H=26; tt=16.f; }
    else { src=o52; anch=a52; H=52; tt=8.f; }
    int HW = H*H;
    int a  = cidx % 3;
    int hw = (cidx/3) % HW;
    int n  = cidx / (3*HW);
    int hh = hw / H;
    int ww = hw - hh*H;
    const float* cellbase = src + (size_t)(n*255 + a*85)*HW + hw;
    // argmax over 80 classes, tie -> lowest class index
    float bv = cellbase[(size_t)(5 + lane)*HW];
    int bi = lane;
    if (lane < 16){
        float v2 = cellbase[(size_t)(69 + lane)*HW];
        if (v2 > bv){ bv = v2; bi = 64 + lane; }
    }
    #pragma unroll
    for (int off=32; off; off>>=1){
        float vo = __shfl_xor(bv, off);
        int io = __shfl_xor(bi, off);
        if (vo > bv || (vo == bv && io < bi)){ bv = vo; bi = io; }
    }
    if (lane == 0){
        float v1 = cellbase[(size_t)1*HW];
        float v2 = cellbase[(size_t)2*HW];
        float v3 = cellbase[(size_t)3*HW];
        float v4 = cellbase[(size_t)4*HW];
        float cx = ((float)ww + v1) * tt / 416.0f;
        float cy = ((float)hh + v2) * tt / 416.0f;
        float e3 = (float)exp((double)v3);
        float e4 = (float)exp((double)v4);
        float bw = anch[a*2+0] * e3 / 416.0f;
        float bh = anch[a*2+1] * e4 / 416.0f;
        row[0] = (float)n;  row[1] = cx; row[2] = cy; row[3] = bw; row[4] = bh;
        row[5] = u2f(sbits); row[6] = (float)bi; row[7] = (float)hh; row[8] = (float)ww;
    }
}

__global__ void __launch_bounds__(1024) k_sort(const unsigned long long* __restrict__ sel,
                       const float* __restrict__ boxes, float* __restrict__ sboxes,
                       unsigned long long* __restrict__ vwords){
    __shared__ unsigned long long sk[2048];
    int t = threadIdx.x;
    for (int r=t; r<2048; r+=1024)
        sk[r] = (r < NBOX) ? ((sel[r] << 12) | (unsigned long long)r) : 0ull;
    __syncthreads();
    for (int k=2; k<=2048; k<<=1)
        for (int j=k>>1; j>0; j>>=1){
            for (int i=t; i<2048; i+=1024){
                int ixj = i ^ j;
                if (ixj > i){
                    bool up = ((i & k) == 0);
                    unsigned long long a = sk[i], b = sk[ixj];
                    if (up ? (a < b) : (a > b)){ sk[i] = b; sk[ixj] = a; }
                }
            }
            __syncthreads();
        }
    for (int r=t; r<2048; r+=1024){
        if (r < NBOX){
            unsigned long long key = sk[r];
            bool valid = (key >> 32) != 0ull;     // top 32 bits = sigmoid bits
            int slot = (int)(key & 0xFFFull);
            #pragma unroll
            for (int c=0;c<9;c++) sboxes[r*12+c] = valid ? boxes[slot*12+c] : 0.f;
            unsigned long long ball = __ballot(valid);
            if ((r & 63) == 0) vwords[r >> 6] = ball;
        }
    }
}

__global__ void k_masks(const float* __restrict__ sboxes, unsigned long long* __restrict__ sup){
    int i = blockIdx.x;
    int lane = threadIdx.x;
    float cxi = sboxes[i*12+1], cyi = sboxes[i*12+2], wi = sboxes[i*12+3], hi = sboxes[i*12+4];
    float x1i = cxi - wi/2.0f, y1i = cyi - hi/2.0f, x2i = cxi + wi/2.0f, y2i = cyi + hi/2.0f;
    float ari = fmaxf(x2i-x1i, 0.f) * fmaxf(y2i-y1i, 0.f);
    for (int c=0; c<24; c++){
        int j = c*64 + lane;
        float cxj = sboxes[j*12+1], cyj = sboxes[j*12+2], wj = sboxes[j*12+3], hj = sboxes[j*12+4];
        float x1j = cxj - wj/2.0f, y1j = cyj - hj/2.0f, x2j = cxj + wj/2.0f, y2j = cyj + hj/2.0f;
        float arj = fmaxf(x2j-x1j, 0.f) * fmaxf(y2j-y1j, 0.f);
        float ix = fmaxf(0.f, fminf(x2i, x2j) - fmaxf(x1i, x1j));
        float iy = fmaxf(0.f, fminf(y2i, y2j) - fmaxf(y1i, y1j));
        float inter = ix * iy;
        float iou = inter / fmaxf(fminf(ari, arj), 1e-9f);
        bool sb = (iou > 0.7f) && (j > i);
        unsigned long long ball = __ballot(sb);
        if (lane == 0) sup[i*24 + c] = ball;
    }
}

// Two-level greedy NMS scan: intra-tile 64x64 resolve in registers (no shuffles
// in the dependency chain), then pipelined cross-tile row ORs.
__global__ void k_nms_out(const float* __restrict__ sboxes, const unsigned long long* __restrict__ vwords,
                          const unsigned long long* __restrict__ sup, float* __restrict__ out){
    __shared__ unsigned long long keepw[24];
    int t = threadIdx.x;
    if (t < 64){
        int lane = t;
        unsigned long long rem = 0ull;      // lane<24: removed-columns word `lane`
        for (int g=0; g<24; g++){
            // replicated diagonal block (wave-uniform broadcast loads, static regs)
            unsigned long long D[64];
            #pragma unroll
            for (int i=0;i<64;i++) D[i] = sup[(size_t)(g*64+i)*24 + g];
            unsigned long long vcur = vwords[g];                 // broadcast load
            unsigned long long cur = __shfl(rem, g);             // prior-tile suppressions
            #pragma unroll
            for (int i=0;i<64;i++){
                bool alive = (((vcur >> i) & 1ull) != 0ull) && (((cur >> i) & 1ull) == 0ull);
                cur |= alive ? D[i] : 0ull;
            }
            unsigned long long aliveW = vcur & ~cur;             // wave-uniform
            if (lane == 0) keepw[g] = aliveW;
            // cross-tile: OR kept boxes' suppression rows into rem (independent loads)
            if (lane < 24){
                #pragma unroll
                for (int i=0;i<64;i++){
                    unsigned long long row = sup[(size_t)(g*64+i)*24 + lane];
                    rem |= (((aliveW >> i) & 1ull) != 0ull) ? row : 0ull;
                }
            }
        }
    }
    __syncthreads();
    for (int e=t; e<NBOX*9; e+=256){
        int r = e / 9;
        int c = e - r*9;
        bool kp = ((keepw[r >> 6] >> (r & 63)) & 1ull) != 0ull;
        out[e] = kp ? sboxes[r*12 + c] : 0.f;
    }
}

extern "C" void kernel_launch(void* const* d_in, const int* in_sizes, int n_in,
                              void* d_out, int out_size, void* d_ws, size_t ws_size,
                              hipStream_t stream){
    const float* o13 = (const float*)d_in[0];
    const float* o26 = (const float*)d_in[1];
    const float* o52 = (const float*)d_in[2];
    const float* a13 = (const float*)d_in[3];
    const float* a26 = (const float*)d_in[4];
    const float* a52 = (const float*)d_in[5];
    char* ws = (char*)d_ws;
    unsigned long long* cand  = (unsigned long long*)(ws);              // 344064*8 = 2,752,512
    int* hist                 = (int*)(ws + 2752512);                   // 49,152
    int* cnt                  = (int*)(ws + 2801664);                   // 256
    unsigned long long* sel   = (unsigned long long*)(ws + 2801920);    // 12,288
    unsigned long long* stash = (unsigned long long*)(ws + 2814208);    // 24,576
    float* boxes              = (float*)(ws + 2838784);                 // 73,728
    float* sboxes             = (float*)(ws + 2912512);                 // 73,728
    unsigned long long* vw    = (unsigned long long*)(ws + 2986240);    // 256
    unsigned long long* sup   = (unsigned long long*)(ws + 2986496);    // 294,912 (end ~3.28 MB)
    float* out = (float*)d_out;

    k_init    <<<48, 256, 0, stream>>>(hist, cnt);
    k_score   <<<(TOTCELL + 255)/256, 256, 0, stream>>>(o13, o26, o52, cand, cnt, hist);
    k_cutoff  <<<3, 1024, 0, stream>>>(hist, cnt);
    k_classify<<<CAND_CAP/256, 256, 0, stream>>>(cand, cnt, sel, stash);
    k_finalize<<<3, 1024, 0, stream>>>(cnt, sel, stash);
    k_decode  <<<NBOX/4, 256, 0, stream>>>(o13, o26, o52, a13, a26, a52, sel, boxes);
    k_sort    <<<1, 1024, 0, stream>>>(sel, boxes, sboxes, vw);
    k_masks   <<<NBOX, 64, 0, stream>>>(sboxes, sup);
    k_nms_out <<<1, 256, 0, stream>>>(sboxes, vw, sup, out);
}

// Round 4
// 410.493 us; speedup vs baseline: 1.2161x; 1.2161x over previous
//
#include <hip/hip_runtime.h>
#include <stdint.h>

#define KPS 512
#define NBOX 1536
#define NBINS 4096

// scale cell counts: 32*H*H*3
#define S13 16224
#define S26 64896
#define S52 259584
#define TOTCELL 340704

// candidate segment bases/caps (in keys)
#define C13_BASE 0
#define C26_BASE 16384
#define C52_BASE 81920
#define CAND_CAP 344064

__device__ __forceinline__ uint32_t f2u(float x){ union{float f;uint32_t u;}v; v.f=x; return v.u; }
__device__ __forceinline__ float u2f(uint32_t x){ union{float f;uint32_t u;}v; v.u=x; return v.f; }

__device__ __forceinline__ int binOf(float s){
    int b = (int)((s - 0.6f) * 10240.0f);
    if (b < 0) b = 0;
    if (b > NBINS-1) b = NBINS-1;
    return b;
}

// counters: [0..2] candCnt, [3..5] abovePos, [6..8] stashCnt, [9..11] cutoffB, [12..14] aboveCount
__global__ void k_init(int* hist, int* cnt, unsigned long long* diagT){
    int id = blockIdx.x*256 + threadIdx.x;
    if (id < 3*NBINS) hist[id] = 0;
    if (id < 32) cnt[id] = 0;
    if (id < NBOX) diagT[id] = 0ull;
}

__global__ void k_score(const float* __restrict__ o13, const float* __restrict__ o26,
                        const float* __restrict__ o52,
                        unsigned long long* __restrict__ cand, int* __restrict__ cnt,
                        int* __restrict__ hist){
    int id = blockIdx.x*256 + threadIdx.x;
    bool live = (id < TOTCELL);
    int scale=0, idl=0, H=13, segbase=0;
    const float* src = o13;
    if (live){
        if (id < S13)            { scale=0; idl=id;            H=13; src=o13; segbase=C13_BASE; }
        else if (id < S13+S26)   { scale=1; idl=id-S13;        H=26; src=o26; segbase=C26_BASE; }
        else                     { scale=2; idl=id-(S13+S26);  H=52; src=o52; segbase=C52_BASE; }
    }
    int HW = H*H;
    // plane-major thread mapping for coalescing: idl = p*HW + hw, p = n*3 + a
    int p  = idl / HW;
    int hw = idl - p*HW;
    int n  = p / 3;
    int a  = p - n*3;
    int cidx = (n*HW + hw)*3 + a;       // reference flat cell index
    float s = 0.f;
    if (live){
        float x = src[(size_t)(n*255 + a*85)*HW + hw];
        s = (float)(1.0 / (1.0 + exp(-(double)x)));   // correctly-rounded f32 sigmoid
    }
    bool pred = live && (s > 0.6f);
    int lane = threadIdx.x & 63;
    unsigned long long lanebit_m1 = (lane == 63) ? ~0ull >> 1 : ((1ull << lane) - 1ull);
    // wave-aggregated compaction per scale (waves can straddle scale boundaries)
    #pragma unroll
    for (int sc = 0; sc < 3; sc++){
        unsigned long long m = __ballot(pred && scale == sc);
        if (m){
            int leader = __ffsll((long long)m) - 1;
            int base = 0;
            if (lane == leader) base = atomicAdd(&cnt[sc], __popcll(m));
            base = __shfl(base, leader);
            if (pred && scale == sc){
                int pos = base + __popcll(m & lanebit_m1);
                unsigned long long key = ((unsigned long long)f2u(s) << 20)
                                       | ((unsigned long long)(2-scale) << 18)
                                       | (unsigned long long)(262143 - cidx);
                cand[segbase + pos] = key;
            }
        }
    }
    if (pred) atomicAdd(&hist[scale*NBINS + binOf(s)], 1);
}

__global__ void __launch_bounds__(1024) k_cutoff(const int* __restrict__ hist, int* __restrict__ cnt){
    int s = blockIdx.x, t = threadIdx.x;
    __shared__ int h[NBINS];
    __shared__ int suf[1024];
    #pragma unroll
    for (int k=0;k<4;k++) h[t*4+k] = hist[s*NBINS + t*4 + k];
    __syncthreads();
    int part = h[4*t] + h[4*t+1] + h[4*t+2] + h[4*t+3];
    suf[t] = part; __syncthreads();
    for (int d=1; d<1024; d<<=1){
        int v = (t+d < 1024) ? suf[t+d] : 0;
        __syncthreads();
        suf[t] += v;
        __syncthreads();
    }
    int total = suf[0];
    int A = (t < 1023) ? suf[t+1] : 0;
    int ca3 = A;
    int ca2 = A   + h[4*t+3];
    int ca1 = ca2 + h[4*t+2];
    int ca0 = ca1 + h[4*t+1];
    int ca[4] = {ca0, ca1, ca2, ca3};
    if (t == 0 && total < KPS){ cnt[9+s] = -1; cnt[12+s] = total; }
    #pragma unroll
    for (int k=0;k<4;k++){
        int b = 4*t + k;
        if (ca[k] < KPS && ca[k] + h[b] >= KPS){ cnt[9+s] = b; cnt[12+s] = ca[k]; }
    }
}

__global__ void k_classify(const unsigned long long* __restrict__ cand, int* __restrict__ cnt,
                           unsigned long long* __restrict__ sel, unsigned long long* __restrict__ stash){
    int id = blockIdx.x*256 + threadIdx.x;
    int scale, segbase;
    if (id < C26_BASE)      { scale=0; segbase=C13_BASE; }
    else if (id < C52_BASE) { scale=1; segbase=C26_BASE; }
    else                    { scale=2; segbase=C52_BASE; }
    int slot = id - segbase;
    bool live = (id < CAND_CAP) && (slot < cnt[scale]);
    unsigned long long key = live ? cand[id] : 0ull;
    int B = cnt[9+scale];
    int bin = live ? binOf(u2f((uint32_t)(key >> 20))) : -2;
    int lane = threadIdx.x & 63;
    unsigned long long lanebit_m1 = (lane == 63) ? ~0ull >> 1 : ((1ull << lane) - 1ull);
    bool above = live && (bin > B);
    bool bound = live && (bin == B);
    // wave-aggregate both counters (waves may straddle scales; loop scales)
    #pragma unroll
    for (int sc = 0; sc < 3; sc++){
        unsigned long long ma = __ballot(above && scale == sc);
        if (ma){
            int leader = __ffsll((long long)ma) - 1;
            int base = 0;
            if (lane == leader) base = atomicAdd(&cnt[3+sc], __popcll(ma));
            base = __shfl(base, leader);
            if (above && scale == sc)
                sel[sc*KPS + base + __popcll(ma & lanebit_m1)] = key;
        }
        unsigned long long mb = __ballot(bound && scale == sc);
        if (mb){
            int leader = __ffsll((long long)mb) - 1;
            int base = 0;
            if (lane == leader) base = atomicAdd(&cnt[6+sc], __popcll(mb));
            base = __shfl(base, leader);
            if (bound && scale == sc){
                int q = base + __popcll(mb & lanebit_m1);
                if (q < 1024) stash[sc*1024 + q] = key;
            }
        }
    }
}

__global__ void __launch_bounds__(1024) k_finalize(const int* __restrict__ cnt,
                           unsigned long long* __restrict__ sel, const unsigned long long* __restrict__ stash){
    int s = blockIdx.x, t = threadIdx.x;
    __shared__ unsigned long long sk[1024];
    int sc = cnt[6+s]; if (sc > 1024) sc = 1024;
    sk[t] = (t < sc) ? stash[s*1024 + t] : 0ull;
    __syncthreads();
    for (int k=2; k<=1024; k<<=1)
        for (int j=k>>1; j>0; j>>=1){
            int ixj = t ^ j;
            if (ixj > t){
                bool up = ((t & k) == 0);   // descending overall
                unsigned long long a = sk[t], b = sk[ixj];
                if (up ? (a < b) : (a > b)){ sk[t] = b; sk[ixj] = a; }
            }
            __syncthreads();
        }
    int above = cnt[12+s];
    int need = KPS - above; if (need < 0) need = 0;
    int m = (need < sc) ? need : sc;
    if (t < m) sel[s*KPS + above + t] = sk[t];
    if (t >= above + m && t < KPS) sel[s*KPS + t] = 0ull;   // sentinels
}

__global__ void k_decode(const float* __restrict__ o13, const float* __restrict__ o26,
                         const float* __restrict__ o52,
                         const float* __restrict__ a13, const float* __restrict__ a26,
                         const float* __restrict__ a52,
                         const unsigned long long* __restrict__ sel, float* __restrict__ boxes){
    int gtid = blockIdx.x*256 + threadIdx.x;
    int b = gtid >> 6;
    int lane = threadIdx.x & 63;
    if (b >= NBOX) return;
    unsigned long long key = sel[b];
    float* row = boxes + b*12;
    if ((key >> 20) == 0ull){           // sentinel
        if (lane < 9) row[lane] = 0.f;
        return;
    }
    int scale = 2 - (int)((key >> 18) & 3ull);
    int cidx  = 262143 - (int)(key & 0x3FFFFull);
    uint32_t sbits = (uint32_t)(key >> 20);
    const float* src; const float* anch; int H; float tt;
    if (scale == 0){ src=o13; anch=a13; H=13; tt=32.f; }
    else if (scale == 1){ src=o26; anch=a26; H=26; tt=16.f; }
    else { src=o52; anch=a52; H=52; tt=8.f; }
    int HW = H*H;
    int a  = cidx % 3;
    int hw = (cidx/3) % HW;
    int n  = cidx / (3*HW);
    int hh = hw / H;
    int ww = hw - hh*H;
    const float* cellbase = src + (size_t)(n*255 + a*85)*HW + hw;
    // argmax over 80 classes, tie -> lowest class index
    float bv = cellbase[(size_t)(5 + lane)*HW];
    int bi = lane;
    if (lane < 16){
        float v2 = cellbase[(size_t)(69 + lane)*HW];
        if (v2 > bv){ bv = v2; bi = 64 + lane; }
    }
    #pragma unroll
    for (int off=32; off; off>>=1){
        float vo = __shfl_xor(bv, off);
        int io = __shfl_xor(bi, off);
        if (vo > bv || (vo == bv && io < bi)){ bv = vo; bi = io; }
    }
    if (lane == 0){
        float v1 = cellbase[(size_t)1*HW];
        float v2 = cellbase[(size_t)2*HW];
        float v3 = cellbase[(size_t)3*HW];
        float v4 = cellbase[(size_t)4*HW];
        float cx = ((float)ww + v1) * tt / 416.0f;
        float cy = ((float)hh + v2) * tt / 416.0f;
        float e3 = (float)exp((double)v3);
        float e4 = (float)exp((double)v4);
        float bw = anch[a*2+0] * e3 / 416.0f;
        float bh = anch[a*2+1] * e4 / 416.0f;
        row[0] = (float)n;  row[1] = cx; row[2] = cy; row[3] = bw; row[4] = bh;
        row[5] = u2f(sbits); row[6] = (float)bi; row[7] = (float)hh; row[8] = (float)ww;
    }
}

__global__ void __launch_bounds__(1024) k_sort(const unsigned long long* __restrict__ sel,
                       const float* __restrict__ boxes, float* __restrict__ sboxes,
                       unsigned long long* __restrict__ vwords){
    __shared__ unsigned long long sk[2048];
    int t = threadIdx.x;
    for (int r=t; r<2048; r+=1024)
        sk[r] = (r < NBOX) ? ((sel[r] << 12) | (unsigned long long)r) : 0ull;
    __syncthreads();
    for (int k=2; k<=2048; k<<=1)
        for (int j=k>>1; j>0; j>>=1){
            for (int i=t; i<2048; i+=1024){
                int ixj = i ^ j;
                if (ixj > i){
                    bool up = ((i & k) == 0);
                    unsigned long long a = sk[i], b = sk[ixj];
                    if (up ? (a < b) : (a > b)){ sk[i] = b; sk[ixj] = a; }
                }
            }
            __syncthreads();
        }
    for (int r=t; r<2048; r+=1024){
        if (r < NBOX){
            unsigned long long key = sk[r];
            bool valid = (key >> 32) != 0ull;     // top 32 bits = sigmoid bits
            int slot = (int)(key & 0xFFFull);
            #pragma unroll
            for (int c=0;c<9;c++) sboxes[r*12+c] = valid ? boxes[slot*12+c] : 0.f;
            unsigned long long ball = __ballot(valid);
            if ((r & 63) == 0) vwords[r >> 6] = ball;
        }
    }
}

// Column-sliced suppression matrix: Tcol[i*64 + j] bit c = sup(i, c*64+j).
// Diagonal-tile transpose: diagT[g*64 + j] bit i = sup(g*64+i, g*64+j).
__global__ void k_masks(const float* __restrict__ sboxes, unsigned* __restrict__ Tcol,
                        unsigned long long* __restrict__ diagT){
    int i = blockIdx.x;
    int lane = threadIdx.x;
    int gi = i >> 6, ii = i & 63;
    float cxi = sboxes[i*12+1], cyi = sboxes[i*12+2], wi = sboxes[i*12+3], hi = sboxes[i*12+4];
    float x1i = cxi - wi/2.0f, y1i = cyi - hi/2.0f, x2i = cxi + wi/2.0f, y2i = cyi + hi/2.0f;
    float ari = fmaxf(x2i-x1i, 0.f) * fmaxf(y2i-y1i, 0.f);
    unsigned colbits = 0u;
    for (int c=0; c<24; c++){
        int j = c*64 + lane;
        float cxj = sboxes[j*12+1], cyj = sboxes[j*12+2], wj = sboxes[j*12+3], hj = sboxes[j*12+4];
        float x1j = cxj - wj/2.0f, y1j = cyj - hj/2.0f, x2j = cxj + wj/2.0f, y2j = cyj + hj/2.0f;
        float arj = fmaxf(x2j-x1j, 0.f) * fmaxf(y2j-y1j, 0.f);
        float ix = fmaxf(0.f, fminf(x2i, x2j) - fmaxf(x1i, x1j));
        float iy = fmaxf(0.f, fminf(y2i, y2j) - fmaxf(y1i, y1j));
        float inter = ix * iy;
        float iou = inter / fmaxf(fminf(ari, arj), 1e-9f);
        bool sb = (iou > 0.7f) && (j > i);
        colbits |= sb ? (1u << c) : 0u;
    }
    Tcol[(size_t)i*64 + lane] = colbits;
    if ((colbits >> gi) & 1u)
        atomicOr(&diagT[gi*64 + lane], 1ull << ii);
}

// Greedy NMS scan: per-lane alive bool + ballot per kept box (no loads/shuffles
// in the serial chain); cross-tile suppression via one coalesced Tcol load per
// kept box.
__global__ void k_nms_out(const float* __restrict__ sboxes, const unsigned long long* __restrict__ vwords,
                          const unsigned long long* __restrict__ diagT, const unsigned* __restrict__ Tcol,
                          float* __restrict__ out){
    __shared__ unsigned long long keepw[24];
    int t = threadIdx.x;
    if (t < 64){
        int lane = t;
        unsigned SS = 0u;                       // bit g = box g*64+lane suppressed
        unsigned long long Dcol = diagT[lane];  // tile-0 diag column
        unsigned long long vcur = vwords[0];
        for (int g=0; g<24; g++){
            unsigned long long Dnext = (g < 23) ? diagT[(g+1)*64 + lane] : 0ull;
            unsigned long long vnext = (g < 23) ? vwords[g+1] : 0ull;
            bool s = (((vcur >> lane) & 1ull) != 0ull) && (((SS >> g) & 1u) == 0u);
            unsigned long long W = __ballot(s);
            unsigned long long keptW = 0ull, pending = W;
            while (pending){
                int i = __ffsll((long long)pending) - 1;
                keptW |= 1ull << i;
                s = s && (((Dcol >> i) & 1ull) == 0ull);
                W = __ballot(s);
                unsigned long long above = (i == 63) ? 0ull : (~0ull << (i+1));
                pending = W & above;
            }
            if (lane == 0) keepw[g] = keptW;
            unsigned long long kw = keptW;
            while (kw){
                int i = __ffsll((long long)kw) - 1;
                kw &= kw - 1ull;
                SS |= Tcol[(size_t)(g*64 + i)*64 + lane];
            }
            Dcol = Dnext; vcur = vnext;
        }
    }
    __syncthreads();
    for (int e=t; e<NBOX*9; e+=256){
        int r = e / 9;
        int c = e - r*9;
        bool kp = ((keepw[r >> 6] >> (r & 63)) & 1ull) != 0ull;
        out[e] = kp ? sboxes[r*12 + c] : 0.f;
    }
}

extern "C" void kernel_launch(void* const* d_in, const int* in_sizes, int n_in,
                              void* d_out, int out_size, void* d_ws, size_t ws_size,
                              hipStream_t stream){
    const float* o13 = (const float*)d_in[0];
    const float* o26 = (const float*)d_in[1];
    const float* o52 = (const float*)d_in[2];
    const float* a13 = (const float*)d_in[3];
    const float* a26 = (const float*)d_in[4];
    const float* a52 = (const float*)d_in[5];
    char* ws = (char*)d_ws;
    unsigned long long* cand  = (unsigned long long*)(ws);              // 344064*8 = 2,752,512
    unsigned* Tcol            = (unsigned*)(ws);                        // 393,216 — ALIASES cand (cand dead after k_classify)
    int* hist                 = (int*)(ws + 2752512);                   // 49,152
    int* cnt                  = (int*)(ws + 2801664);                   // 256
    unsigned long long* sel   = (unsigned long long*)(ws + 2801920);    // 12,288
    unsigned long long* stash = (unsigned long long*)(ws + 2814208);    // 24,576
    float* boxes              = (float*)(ws + 2838784);                 // 73,728
    float* sboxes             = (float*)(ws + 2912512);                 // 73,728
    unsigned long long* vw    = (unsigned long long*)(ws + 2986240);    // 256
    unsigned long long* diagT = (unsigned long long*)(ws + 2986496);    // 12,288 (end ~3.0 MB)
    float* out = (float*)d_out;

    k_init    <<<48, 256, 0, stream>>>(hist, cnt, diagT);
    k_score   <<<(TOTCELL + 255)/256, 256, 0, stream>>>(o13, o26, o52, cand, cnt, hist);
    k_cutoff  <<<3, 1024, 0, stream>>>(hist, cnt);
    k_classify<<<CAND_CAP/256, 256, 0, stream>>>(cand, cnt, sel, stash);
    k_finalize<<<3, 1024, 0, stream>>>(cnt, sel, stash);
    k_decode  <<<NBOX/4, 256, 0, stream>>>(o13, o26, o52, a13, a26, a52, sel, boxes);
    k_sort    <<<1, 1024, 0, stream>>>(sel, boxes, sboxes, vw);
    k_masks   <<<NBOX, 64, 0, stream>>>(sboxes, Tcol, diagT);
    k_nms_out <<<1, 256, 0, stream>>>(sboxes, vw, diagT, Tcol, out);
}

// Round 5
// 331.131 us; speedup vs baseline: 1.5075x; 1.2397x over previous
//
#include <hip/hip_runtime.h>
#include <stdint.h>

#define KPS 512
#define NBOX 1536
#define NBINS 4096

// scale cell counts: 32*H*H*3
#define S13 16224
#define S26 64896
#define S52 259584
#define TOTCELL 340704

// candidate segment bases/caps (in keys)
#define C13_BASE 0
#define C26_BASE 16384
#define C52_BASE 81920
#define CAND_CAP 344064

__device__ __forceinline__ uint32_t f2u(float x){ union{float f;uint32_t u;}v; v.f=x; return v.u; }
__device__ __forceinline__ float u2f(uint32_t x){ union{float f;uint32_t u;}v; v.u=x; return v.f; }

__device__ __forceinline__ int binOf(float s){
    int b = (int)((s - 0.6f) * 10240.0f);
    if (b < 0) b = 0;
    if (b > NBINS-1) b = NBINS-1;
    return b;
}

// counters: [0..2] candCnt, [3..5] abovePos, [6..8] stashCnt, [9..11] cutoffB, [12..14] aboveCount
__global__ void k_init(int* hist, int* cnt, unsigned long long* diagT){
    int id = blockIdx.x*256 + threadIdx.x;
    if (id < 3*NBINS) hist[id] = 0;
    if (id < 32) cnt[id] = 0;
    if (id < NBOX) diagT[id] = 0ull;
}

__global__ void k_score(const float* __restrict__ o13, const float* __restrict__ o26,
                        const float* __restrict__ o52,
                        unsigned long long* __restrict__ cand, int* __restrict__ cnt,
                        int* __restrict__ hist){
    int id = blockIdx.x*256 + threadIdx.x;
    bool live = (id < TOTCELL);
    int scale=0, idl=0, H=13, segbase=0;
    const float* src = o13;
    if (live){
        if (id < S13)            { scale=0; idl=id;            H=13; src=o13; segbase=C13_BASE; }
        else if (id < S13+S26)   { scale=1; idl=id-S13;        H=26; src=o26; segbase=C26_BASE; }
        else                     { scale=2; idl=id-(S13+S26);  H=52; src=o52; segbase=C52_BASE; }
    }
    int HW = H*H;
    // plane-major thread mapping for coalescing: idl = p*HW + hw, p = n*3 + a
    int p  = idl / HW;
    int hw = idl - p*HW;
    int n  = p / 3;
    int a  = p - n*3;
    int cidx = (n*HW + hw)*3 + a;       // reference flat cell index
    float s = 0.f;
    if (live){
        float x = src[(size_t)(n*255 + a*85)*HW + hw];
        s = (float)(1.0 / (1.0 + exp(-(double)x)));   // correctly-rounded f32 sigmoid
    }
    bool pred = live && (s > 0.6f);
    int lane = threadIdx.x & 63;
    unsigned long long lanebit_m1 = (lane == 63) ? ~0ull >> 1 : ((1ull << lane) - 1ull);
    // wave-aggregated compaction per scale (waves can straddle scale boundaries)
    #pragma unroll
    for (int sc = 0; sc < 3; sc++){
        unsigned long long m = __ballot(pred && scale == sc);
        if (m){
            int leader = __ffsll((long long)m) - 1;
            int base = 0;
            if (lane == leader) base = atomicAdd(&cnt[sc], __popcll(m));
            base = __shfl(base, leader);
            if (pred && scale == sc){
                int pos = base + __popcll(m & lanebit_m1);
                unsigned long long key = ((unsigned long long)f2u(s) << 20)
                                       | ((unsigned long long)(2-scale) << 18)
                                       | (unsigned long long)(262143 - cidx);
                cand[segbase + pos] = key;
            }
        }
    }
    if (pred) atomicAdd(&hist[scale*NBINS + binOf(s)], 1);
}

__global__ void __launch_bounds__(1024) k_cutoff(const int* __restrict__ hist, int* __restrict__ cnt){
    int s = blockIdx.x, t = threadIdx.x;
    __shared__ int h[NBINS];
    __shared__ int suf[1024];
    #pragma unroll
    for (int k=0;k<4;k++) h[t*4+k] = hist[s*NBINS + t*4 + k];
    __syncthreads();
    int part = h[4*t] + h[4*t+1] + h[4*t+2] + h[4*t+3];
    suf[t] = part; __syncthreads();
    for (int d=1; d<1024; d<<=1){
        int v = (t+d < 1024) ? suf[t+d] : 0;
        __syncthreads();
        suf[t] += v;
        __syncthreads();
    }
    int total = suf[0];
    int A = (t < 1023) ? suf[t+1] : 0;
    int ca3 = A;
    int ca2 = A   + h[4*t+3];
    int ca1 = ca2 + h[4*t+2];
    int ca0 = ca1 + h[4*t+1];
    int ca[4] = {ca0, ca1, ca2, ca3};
    if (t == 0 && total < KPS){ cnt[9+s] = -1; cnt[12+s] = total; }
    #pragma unroll
    for (int k=0;k<4;k++){
        int b = 4*t + k;
        if (ca[k] < KPS && ca[k] + h[b] >= KPS){ cnt[9+s] = b; cnt[12+s] = ca[k]; }
    }
}

__global__ void k_classify(const unsigned long long* __restrict__ cand, int* __restrict__ cnt,
                           unsigned long long* __restrict__ sel, unsigned long long* __restrict__ stash){
    int id = blockIdx.x*256 + threadIdx.x;
    int scale, segbase;
    if (id < C26_BASE)      { scale=0; segbase=C13_BASE; }
    else if (id < C52_BASE) { scale=1; segbase=C26_BASE; }
    else                    { scale=2; segbase=C52_BASE; }
    int slot = id - segbase;
    bool live = (id < CAND_CAP) && (slot < cnt[scale]);
    unsigned long long key = live ? cand[id] : 0ull;
    int B = cnt[9+scale];
    int bin = live ? binOf(u2f((uint32_t)(key >> 20))) : -2;
    int lane = threadIdx.x & 63;
    unsigned long long lanebit_m1 = (lane == 63) ? ~0ull >> 1 : ((1ull << lane) - 1ull);
    bool above = live && (bin > B);
    bool bound = live && (bin == B);
    // wave-aggregate both counters (waves may straddle scales; loop scales)
    #pragma unroll
    for (int sc = 0; sc < 3; sc++){
        unsigned long long ma = __ballot(above && scale == sc);
        if (ma){
            int leader = __ffsll((long long)ma) - 1;
            int base = 0;
            if (lane == leader) base = atomicAdd(&cnt[3+sc], __popcll(ma));
            base = __shfl(base, leader);
            if (above && scale == sc)
                sel[sc*KPS + base + __popcll(ma & lanebit_m1)] = key;
        }
        unsigned long long mb = __ballot(bound && scale == sc);
        if (mb){
            int leader = __ffsll((long long)mb) - 1;
            int base = 0;
            if (lane == leader) base = atomicAdd(&cnt[6+sc], __popcll(mb));
            base = __shfl(base, leader);
            if (bound && scale == sc){
                int q = base + __popcll(mb & lanebit_m1);
                if (q < 1024) stash[sc*1024 + q] = key;
            }
        }
    }
}

__global__ void __launch_bounds__(1024) k_finalize(const int* __restrict__ cnt,
                           unsigned long long* __restrict__ sel, const unsigned long long* __restrict__ stash){
    int s = blockIdx.x, t = threadIdx.x;
    __shared__ unsigned long long sk[1024];
    int sc = cnt[6+s]; if (sc > 1024) sc = 1024;
    sk[t] = (t < sc) ? stash[s*1024 + t] : 0ull;
    __syncthreads();
    for (int k=2; k<=1024; k<<=1)
        for (int j=k>>1; j>0; j>>=1){
            int ixj = t ^ j;
            if (ixj > t){
                bool up = ((t & k) == 0);   // descending overall
                unsigned long long a = sk[t], b = sk[ixj];
                if (up ? (a < b) : (a > b)){ sk[t] = b; sk[ixj] = a; }
            }
            __syncthreads();
        }
    int above = cnt[12+s];
    int need = KPS - above; if (need < 0) need = 0;
    int m = (need < sc) ? need : sc;
    if (t < m) sel[s*KPS + above + t] = sk[t];
    if (t >= above + m && t < KPS) sel[s*KPS + t] = 0ull;   // sentinels
}

__global__ void k_decode(const float* __restrict__ o13, const float* __restrict__ o26,
                         const float* __restrict__ o52,
                         const float* __restrict__ a13, const float* __restrict__ a26,
                         const float* __restrict__ a52,
                         const unsigned long long* __restrict__ sel, float* __restrict__ boxes){
    int gtid = blockIdx.x*256 + threadIdx.x;
    int b = gtid >> 6;
    int lane = threadIdx.x & 63;
    if (b >= NBOX) return;
    unsigned long long key = sel[b];
    float* row = boxes + b*12;
    if ((key >> 20) == 0ull){           // sentinel
        if (lane < 9) row[lane] = 0.f;
        return;
    }
    int scale = 2 - (int)((key >> 18) & 3ull);
    int cidx  = 262143 - (int)(key & 0x3FFFFull);
    uint32_t sbits = (uint32_t)(key >> 20);
    const float* src; const float* anch; int H; float tt;
    if (scale == 0){ src=o13; anch=a13; H=13; tt=32.f; }
    else if (scale == 1){ src=o26; anch=a26; H=26; tt=16.f; }
    else { src=o52; anch=a52; H=52; tt=8.f; }
    int HW = H*H;
    int a  = cidx % 3;
    int hw = (cidx/3) % HW;
    int n  = cidx / (3*HW);
    int hh = hw / H;
    int ww = hw - hh*H;
    const float* cellbase = src + (size_t)(n*255 + a*85)*HW + hw;
    // argmax over 80 classes, tie -> lowest class index
    float bv = cellbase[(size_t)(5 + lane)*HW];
    int bi = lane;
    if (lane < 16){
        float v2 = cellbase[(size_t)(69 + lane)*HW];
        if (v2 > bv){ bv = v2; bi = 64 + lane; }
    }
    #pragma unroll
    for (int off=32; off; off>>=1){
        float vo = __shfl_xor(bv, off);
        int io = __shfl_xor(bi, off);
        if (vo > bv || (vo == bv && io < bi)){ bv = vo; bi = io; }
    }
    if (lane == 0){
        float v1 = cellbase[(size_t)1*HW];
        float v2 = cellbase[(size_t)2*HW];
        float v3 = cellbase[(size_t)3*HW];
        float v4 = cellbase[(size_t)4*HW];
        float cx = ((float)ww + v1) * tt / 416.0f;
        float cy = ((float)hh + v2) * tt / 416.0f;
        float e3 = (float)exp((double)v3);
        float e4 = (float)exp((double)v4);
        float bw = anch[a*2+0] * e3 / 416.0f;
        float bh = anch[a*2+1] * e4 / 416.0f;
        row[0] = (float)n;  row[1] = cx; row[2] = cy; row[3] = bw; row[4] = bh;
        row[5] = u2f(sbits); row[6] = (float)bi; row[7] = (float)hh; row[8] = (float)ww;
    }
}

__global__ void __launch_bounds__(1024) k_sort(const unsigned long long* __restrict__ sel,
                       const float* __restrict__ boxes, float* __restrict__ sboxes,
                       unsigned long long* __restrict__ vwords){
    __shared__ unsigned long long sk[2048];
    int t = threadIdx.x;
    for (int r=t; r<2048; r+=1024)
        sk[r] = (r < NBOX) ? ((sel[r] << 12) | (unsigned long long)r) : 0ull;
    __syncthreads();
    for (int k=2; k<=2048; k<<=1)
        for (int j=k>>1; j>0; j>>=1){
            for (int i=t; i<2048; i+=1024){
                int ixj = i ^ j;
                if (ixj > i){
                    bool up = ((i & k) == 0);
                    unsigned long long a = sk[i], b = sk[ixj];
                    if (up ? (a < b) : (a > b)){ sk[i] = b; sk[ixj] = a; }
                }
            }
            __syncthreads();
        }
    for (int r=t; r<2048; r+=1024){
        if (r < NBOX){
            unsigned long long key = sk[r];
            bool valid = (key >> 32) != 0ull;     // top 32 bits = sigmoid bits
            int slot = (int)(key & 0xFFFull);
            #pragma unroll
            for (int c=0;c<9;c++) sboxes[r*12+c] = valid ? boxes[slot*12+c] : 0.f;
            unsigned long long ball = __ballot(valid);
            if ((r & 63) == 0) vwords[r >> 6] = ball;
        }
    }
}

// Column-sliced suppression matrix: Tcol[i*64 + j] bit c = sup(i, c*64+j).
// Diagonal-tile transpose: diagT[g*64 + j] bit i = sup(g*64+i, g*64+j).
__global__ void k_masks(const float* __restrict__ sboxes, unsigned* __restrict__ Tcol,
                        unsigned long long* __restrict__ diagT){
    int i = blockIdx.x;
    int lane = threadIdx.x;
    int gi = i >> 6, ii = i & 63;
    float cxi = sboxes[i*12+1], cyi = sboxes[i*12+2], wi = sboxes[i*12+3], hi = sboxes[i*12+4];
    float x1i = cxi - wi/2.0f, y1i = cyi - hi/2.0f, x2i = cxi + wi/2.0f, y2i = cyi + hi/2.0f;
    float ari = fmaxf(x2i-x1i, 0.f) * fmaxf(y2i-y1i, 0.f);
    unsigned colbits = 0u;
    for (int c=0; c<24; c++){
        int j = c*64 + lane;
        float cxj = sboxes[j*12+1], cyj = sboxes[j*12+2], wj = sboxes[j*12+3], hj = sboxes[j*12+4];
        float x1j = cxj - wj/2.0f, y1j = cyj - hj/2.0f, x2j = cxj + wj/2.0f, y2j = cyj + hj/2.0f;
        float arj = fmaxf(x2j-x1j, 0.f) * fmaxf(y2j-y1j, 0.f);
        float ix = fmaxf(0.f, fminf(x2i, x2j) - fmaxf(x1i, x1j));
        float iy = fmaxf(0.f, fminf(y2i, y2j) - fmaxf(y1i, y1j));
        float inter = ix * iy;
        float iou = inter / fmaxf(fminf(ari, arj), 1e-9f);
        bool sb = (iou > 0.7f) && (j > i);
        colbits |= sb ? (1u << c) : 0u;
    }
    Tcol[(size_t)i*64 + lane] = colbits;
    if ((colbits >> gi) & 1u)
        atomicOr(&diagT[gi*64 + lane], 1ull << ii);
}

// Greedy NMS scan. Wave 0 resolves each 64-box tile with a ballot-only chain;
// then ALL 4 waves cooperatively OR the kept rows' Tcol words (16 independent
// predicated loads per lane, one waitcnt) and merge partials through LDS.
__global__ void k_nms_out(const float* __restrict__ sboxes, const unsigned long long* __restrict__ vwords,
                          const unsigned long long* __restrict__ diagT, const unsigned* __restrict__ Tcol,
                          float* __restrict__ out){
    __shared__ unsigned long long keepw[24];
    __shared__ unsigned partial[4][64];
    int t = threadIdx.x;
    int wv = t >> 6, lane = t & 63;
    unsigned SS = 0u;                        // wave0 lanes: bit g = box g*64+lane suppressed
    unsigned long long Dcol = 0ull, vcur = 0ull;
    if (wv == 0){ Dcol = diagT[lane]; vcur = vwords[0]; }
    for (int g = 0; g < 24; g++){
        if (wv == 0){
            unsigned long long Dnext = (g < 23) ? diagT[(g+1)*64 + lane] : 0ull;
            unsigned long long vnext = (g < 23) ? vwords[g+1] : 0ull;
            bool s = (((vcur >> lane) & 1ull) != 0ull) && (((SS >> g) & 1u) == 0u);
            unsigned long long W = __ballot(s);
            unsigned long long keptW = 0ull, pending = W;
            while (pending){
                int i = __ffsll((long long)pending) - 1;
                keptW |= 1ull << i;
                s = s && (((Dcol >> i) & 1ull) == 0ull);
                W = __ballot(s);
                unsigned long long above = (i == 63) ? 0ull : (~0ull << (i+1));
                pending = W & above;
            }
            if (lane == 0) keepw[g] = keptW;
            Dcol = Dnext; vcur = vnext;
        }
        __syncthreads();                      // keepw[g] visible to all waves
        unsigned long long keptW = keepw[g];
        unsigned kbits = (unsigned)((keptW >> (wv*16)) & 0xFFFFull);   // wave-uniform
        const unsigned* base = Tcol + (size_t)(g*64 + wv*16)*64 + lane;
        unsigned a0=0u, a1=0u, a2=0u, a3=0u;
        #pragma unroll
        for (int i=0; i<4; i++){
            unsigned r0 = base[(i*4+0)*64];
            unsigned r1 = base[(i*4+1)*64];
            unsigned r2 = base[(i*4+2)*64];
            unsigned r3 = base[(i*4+3)*64];
            a0 |= (0u - ((kbits >> (i*4+0)) & 1u)) & r0;
            a1 |= (0u - ((kbits >> (i*4+1)) & 1u)) & r1;
            a2 |= (0u - ((kbits >> (i*4+2)) & 1u)) & r2;
            a3 |= (0u - ((kbits >> (i*4+3)) & 1u)) & r3;
        }
        partial[wv][lane] = (a0 | a1) | (a2 | a3);
        __syncthreads();                      // partials visible
        if (wv == 0)
            SS |= partial[0][lane] | partial[1][lane] | partial[2][lane] | partial[3][lane];
    }
    for (int e=t; e<NBOX*9; e+=256){
        int r = e / 9;
        int c = e - r*9;
        bool kp = ((keepw[r >> 6] >> (r & 63)) & 1ull) != 0ull;
        out[e] = kp ? sboxes[r*12 + c] : 0.f;
    }
}

extern "C" void kernel_launch(void* const* d_in, const int* in_sizes, int n_in,
                              void* d_out, int out_size, void* d_ws, size_t ws_size,
                              hipStream_t stream){
    const float* o13 = (const float*)d_in[0];
    const float* o26 = (const float*)d_in[1];
    const float* o52 = (const float*)d_in[2];
    const float* a13 = (const float*)d_in[3];
    const float* a26 = (const float*)d_in[4];
    const float* a52 = (const float*)d_in[5];
    char* ws = (char*)d_ws;
    unsigned long long* cand  = (unsigned long long*)(ws);              // 344064*8 = 2,752,512
    unsigned* Tcol            = (unsigned*)(ws);                        // 393,216 — ALIASES cand (cand dead after k_classify)
    int* hist                 = (int*)(ws + 2752512);                   // 49,152
    int* cnt                  = (int*)(ws + 2801664);                   // 256
    unsigned long long* sel   = (unsigned long long*)(ws + 2801920);    // 12,288
    unsigned long long* stash = (unsigned long long*)(ws + 2814208);    // 24,576
    float* boxes              = (float*)(ws + 2838784);                 // 73,728
    float* sboxes             = (float*)(ws + 2912512);                 // 73,728
    unsigned long long* vw    = (unsigned long long*)(ws + 2986240);    // 256
    unsigned long long* diagT = (unsigned long long*)(ws + 2986496);    // 12,288 (end ~3.0 MB)
    float* out = (float*)d_out;

    k_init    <<<48, 256, 0, stream>>>(hist, cnt, diagT);
    k_score   <<<(TOTCELL + 255)/256, 256, 0, stream>>>(o13, o26, o52, cand, cnt, hist);
    k_cutoff  <<<3, 1024, 0, stream>>>(hist, cnt);
    k_classify<<<CAND_CAP/256, 256, 0, stream>>>(cand, cnt, sel, stash);
    k_finalize<<<3, 1024, 0, stream>>>(cnt, sel, stash);
    k_decode  <<<NBOX/4, 256, 0, stream>>>(o13, o26, o52, a13, a26, a52, sel, boxes);
    k_sort    <<<1, 1024, 0, stream>>>(sel, boxes, sboxes, vw);
    k_masks   <<<NBOX, 64, 0, stream>>>(sboxes, Tcol, diagT);
    k_nms_out <<<1, 256, 0, stream>>>(sboxes, vw, diagT, Tcol, out);
}

// Round 6
// 309.528 us; speedup vs baseline: 1.6127x; 1.0698x over previous
//
#include <hip/hip_runtime.h>
#include <stdint.h>

#define KPS 512
#define NBOX 1536
#define NBINS 1024

// scale cell counts: 32*H*H*3
#define S13 16224
#define S26 64896
#define S52 259584
#define TOTCELL 340704

__device__ __forceinline__ uint32_t f2u(float x){ union{float f;uint32_t u;}v; v.f=x; return v.u; }
__device__ __forceinline__ float u2f(uint32_t x){ union{float f;uint32_t u;}v; v.u=x; return v.f; }

__device__ __forceinline__ int binOf(float s){
    int b = (int)((s - 0.6f) * 2560.0f);    // 1024 bins over (0.6, 1.0)
    if (b < 0) b = 0;
    if (b > NBINS-1) b = NBINS-1;
    return b;
}

// counters: [3..5] abovePos, [6..8] stashCnt, [9..11] cutoffB, [12..14] aboveCount
__global__ void k_init(int* hist, int* cnt, unsigned long long* diagT){
    int id = blockIdx.x*256 + threadIdx.x;
    if (id < 3*NBINS) hist[id] = 0;
    if (id < 32) cnt[id] = 0;
    if (id < NBOX) diagT[id] = 0ull;
}

// Sparse candidate slots: cand[id] = key or 0. No wave-stalling atomics.
__global__ void k_score(const float* __restrict__ o13, const float* __restrict__ o26,
                        const float* __restrict__ o52,
                        unsigned long long* __restrict__ cand, int* __restrict__ hist){
    int id = blockIdx.x*256 + threadIdx.x;
    if (id >= TOTCELL) return;
    int scale, idl, H;
    const float* src;
    if (id < S13)            { scale=0; idl=id;            H=13; src=o13; }
    else if (id < S13+S26)   { scale=1; idl=id-S13;        H=26; src=o26; }
    else                     { scale=2; idl=id-(S13+S26);  H=52; src=o52; }
    int HW = H*H;
    // plane-major thread mapping for coalescing: idl = p*HW + hw, p = n*3 + a
    int p  = idl / HW;
    int hw = idl - p*HW;
    int n  = p / 3;
    int a  = p - n*3;
    int cidx = (n*HW + hw)*3 + a;       // reference flat cell index
    float x = src[(size_t)(n*255 + a*85)*HW + hw];
    float s = (float)(1.0 / (1.0 + exp(-(double)x)));   // correctly-rounded f32 sigmoid
    unsigned long long key = 0ull;
    if (s > 0.6f){
        key = ((unsigned long long)f2u(s) << 20)
            | ((unsigned long long)(2-scale) << 18)
            | (unsigned long long)(262143 - cidx);
        atomicAdd(&hist[scale*NBINS + binOf(s)], 1);   // fire-and-forget, spread bins
    }
    cand[id] = key;
}

__global__ void __launch_bounds__(1024) k_cutoff(const int* __restrict__ hist, int* __restrict__ cnt){
    int s = blockIdx.x, t = threadIdx.x;
    __shared__ int suf[NBINS];
    int h = hist[s*NBINS + t];
    suf[t] = h; __syncthreads();
    for (int d=1; d<NBINS; d<<=1){
        int v = (t+d < NBINS) ? suf[t+d] : 0;
        __syncthreads();
        suf[t] += v;
        __syncthreads();
    }
    int total = suf[0];
    int A = (t < NBINS-1) ? suf[t+1] : 0;   // count strictly above bin t
    if (t == 0 && total < KPS){ cnt[9+s] = -1; cnt[12+s] = total; }
    if (A < KPS && A + h >= KPS){ cnt[9+s] = t; cnt[12+s] = A; }
}

__global__ void k_classify(const unsigned long long* __restrict__ cand, int* __restrict__ cnt,
                           unsigned long long* __restrict__ sel, unsigned long long* __restrict__ stash){
    int id = blockIdx.x*256 + threadIdx.x;
    unsigned long long key = (id < TOTCELL) ? cand[id] : 0ull;
    bool live = (key != 0ull);
    int scale = live ? (2 - (int)((key >> 18) & 3ull)) : 0;
    int bin = live ? binOf(u2f((uint32_t)(key >> 20))) : -2;
    int B = cnt[9+scale];
    int lane = threadIdx.x & 63;
    unsigned long long lanebit_m1 = (lane == 63) ? ~0ull >> 1 : ((1ull << lane) - 1ull);
    bool above = live && (bin > B);
    bool bound = live && (bin == B);
    // wave-aggregate both counters (waves may straddle scales; loop scales)
    #pragma unroll
    for (int sc = 0; sc < 3; sc++){
        unsigned long long ma = __ballot(above && scale == sc);
        if (ma){
            int leader = __ffsll((long long)ma) - 1;
            int base = 0;
            if (lane == leader) base = atomicAdd(&cnt[3+sc], __popcll(ma));
            base = __shfl(base, leader);
            if (above && scale == sc)
                sel[sc*KPS + base + __popcll(ma & lanebit_m1)] = key;
        }
        unsigned long long mb = __ballot(bound && scale == sc);
        if (mb){
            int leader = __ffsll((long long)mb) - 1;
            int base = 0;
            if (lane == leader) base = atomicAdd(&cnt[6+sc], __popcll(mb));
            base = __shfl(base, leader);
            if (bound && scale == sc){
                int q = base + __popcll(mb & lanebit_m1);
                if (q < 1024) stash[sc*1024 + q] = key;
            }
        }
    }
}

__global__ void __launch_bounds__(1024) k_finalize(const int* __restrict__ cnt,
                           unsigned long long* __restrict__ sel, const unsigned long long* __restrict__ stash){
    int s = blockIdx.x, t = threadIdx.x;
    __shared__ unsigned long long sk[1024];
    int sc = cnt[6+s]; if (sc > 1024) sc = 1024;
    sk[t] = (t < sc) ? stash[s*1024 + t] : 0ull;
    __syncthreads();
    for (int k=2; k<=1024; k<<=1)
        for (int j=k>>1; j>0; j>>=1){
            int ixj = t ^ j;
            if (ixj > t){
                bool up = ((t & k) == 0);   // descending overall
                unsigned long long a = sk[t], b = sk[ixj];
                if (up ? (a < b) : (a > b)){ sk[t] = b; sk[ixj] = a; }
            }
            __syncthreads();
        }
    int above = cnt[12+s];
    int need = KPS - above; if (need < 0) need = 0;
    int m = (need < sc) ? need : sc;
    if (t < m) sel[s*KPS + above + t] = sk[t];
    if (t >= above + m && t < KPS) sel[s*KPS + t] = 0ull;   // sentinels
}

__global__ void k_decode(const float* __restrict__ o13, const float* __restrict__ o26,
                         const float* __restrict__ o52,
                         const float* __restrict__ a13, const float* __restrict__ a26,
                         const float* __restrict__ a52,
                         const unsigned long long* __restrict__ sel, float* __restrict__ boxes){
    int gtid = blockIdx.x*256 + threadIdx.x;
    int b = gtid >> 6;
    int lane = threadIdx.x & 63;
    if (b >= NBOX) return;
    unsigned long long key = sel[b];
    float* row = boxes + b*12;
    if ((key >> 20) == 0ull){           // sentinel
        if (lane < 9) row[lane] = 0.f;
        return;
    }
    int scale = 2 - (int)((key >> 18) & 3ull);
    int cidx  = 262143 - (int)(key & 0x3FFFFull);
    uint32_t sbits = (uint32_t)(key >> 20);
    const float* src; const float* anch; int H; float tt;
    if (scale == 0){ src=o13; anch=a13; H=13; tt=32.f; }
    else if (scale == 1){ src=o26; anch=a26; H=26; tt=16.f; }
    else { src=o52; anch=a52; H=52; tt=8.f; }
    int HW = H*H;
    int a  = cidx % 3;
    int hw = (cidx/3) % HW;
    int n  = cidx / (3*HW);
    int hh = hw / H;
    int ww = hw - hh*H;
    const float* cellbase = src + (size_t)(n*255 + a*85)*HW + hw;
    // argmax over 80 classes, tie -> lowest class index
    float bv = cellbase[(size_t)(5 + lane)*HW];
    int bi = lane;
    if (lane < 16){
        float v2 = cellbase[(size_t)(69 + lane)*HW];
        if (v2 > bv){ bv = v2; bi = 64 + lane; }
    }
    #pragma unroll
    for (int off=32; off; off>>=1){
        float vo = __shfl_xor(bv, off);
        int io = __shfl_xor(bi, off);
        if (vo > bv || (vo == bv && io < bi)){ bv = vo; bi = io; }
    }
    if (lane == 0){
        float v1 = cellbase[(size_t)1*HW];
        float v2 = cellbase[(size_t)2*HW];
        float v3 = cellbase[(size_t)3*HW];
        float v4 = cellbase[(size_t)4*HW];
        float cx = ((float)ww + v1) * tt / 416.0f;
        float cy = ((float)hh + v2) * tt / 416.0f;
        float e3 = (float)exp((double)v3);
        float e4 = (float)exp((double)v4);
        float bw = anch[a*2+0] * e3 / 416.0f;
        float bh = anch[a*2+1] * e4 / 416.0f;
        row[0] = (float)n;  row[1] = cx; row[2] = cy; row[3] = bw; row[4] = bh;
        row[5] = u2f(sbits); row[6] = (float)bi; row[7] = (float)hh; row[8] = (float)ww;
    }
}

__global__ void __launch_bounds__(1024) k_sort(const unsigned long long* __restrict__ sel,
                       const float* __restrict__ boxes, float* __restrict__ sboxes,
                       unsigned long long* __restrict__ vwords){
    __shared__ unsigned long long sk[2048];
    int t = threadIdx.x;
    for (int r=t; r<2048; r+=1024)
        sk[r] = (r < NBOX) ? ((sel[r] << 12) | (unsigned long long)r) : 0ull;
    __syncthreads();
    for (int k=2; k<=2048; k<<=1)
        for (int j=k>>1; j>0; j>>=1){
            for (int i=t; i<2048; i+=1024){
                int ixj = i ^ j;
                if (ixj > i){
                    bool up = ((i & k) == 0);
                    unsigned long long a = sk[i], b = sk[ixj];
                    if (up ? (a < b) : (a > b)){ sk[i] = b; sk[ixj] = a; }
                }
            }
            __syncthreads();
        }
    for (int r=t; r<2048; r+=1024){
        if (r < NBOX){
            unsigned long long key = sk[r];
            bool valid = (key >> 32) != 0ull;     // top 32 bits = sigmoid bits
            int slot = (int)(key & 0xFFFull);
            #pragma unroll
            for (int c=0;c<9;c++) sboxes[r*12+c] = valid ? boxes[slot*12+c] : 0.f;
            unsigned long long ball = __ballot(valid);
            if ((r & 63) == 0) vwords[r >> 6] = ball;
        }
    }
}

// Column-sliced suppression matrix: Tcol[i*64 + j] bit c = sup(i, c*64+j).
// Diagonal-tile transpose: diagT[g*64 + j] bit i = sup(g*64+i, g*64+j).
__global__ void k_masks(const float* __restrict__ sboxes, unsigned* __restrict__ Tcol,
                        unsigned long long* __restrict__ diagT){
    int i = blockIdx.x;
    int lane = threadIdx.x;
    int gi = i >> 6, ii = i & 63;
    float cxi = sboxes[i*12+1], cyi = sboxes[i*12+2], wi = sboxes[i*12+3], hi = sboxes[i*12+4];
    float x1i = cxi - wi/2.0f, y1i = cyi - hi/2.0f, x2i = cxi + wi/2.0f, y2i = cyi + hi/2.0f;
    float ari = fmaxf(x2i-x1i, 0.f) * fmaxf(y2i-y1i, 0.f);
    unsigned colbits = 0u;
    for (int c=0; c<24; c++){
        int j = c*64 + lane;
        float cxj = sboxes[j*12+1], cyj = sboxes[j*12+2], wj = sboxes[j*12+3], hj = sboxes[j*12+4];
        float x1j = cxj - wj/2.0f, y1j = cyj - hj/2.0f, x2j = cxj + wj/2.0f, y2j = cyj + hj/2.0f;
        float arj = fmaxf(x2j-x1j, 0.f) * fmaxf(y2j-y1j, 0.f);
        float ix = fmaxf(0.f, fminf(x2i, x2j) - fmaxf(x1i, x1j));
        float iy = fmaxf(0.f, fminf(y2i, y2j) - fmaxf(y1i, y1j));
        float inter = ix * iy;
        float iou = inter / fmaxf(fminf(ari, arj), 1e-9f);
        bool sb = (iou > 0.7f) && (j > i);
        colbits |= sb ? (1u << c) : 0u;
    }
    Tcol[(size_t)i*64 + lane] = colbits;
    if ((colbits >> gi) & 1u)
        atomicOr(&diagT[gi*64 + lane], 1ull << ii);
}

// Greedy NMS scan. Wave 0 resolves each 64-box tile with a ballot-only chain;
// then ALL 4 waves cooperatively OR the kept rows' Tcol words (16 independent
// predicated loads per lane, one waitcnt) and merge partials through LDS.
__global__ void k_nms_out(const float* __restrict__ sboxes, const unsigned long long* __restrict__ vwords,
                          const unsigned long long* __restrict__ diagT, const unsigned* __restrict__ Tcol,
                          float* __restrict__ out){
    __shared__ unsigned long long keepw[24];
    __shared__ unsigned partial[4][64];
    int t = threadIdx.x;
    int wv = t >> 6, lane = t & 63;
    unsigned SS = 0u;                        // wave0 lanes: bit g = box g*64+lane suppressed
    unsigned long long Dcol = 0ull, vcur = 0ull;
    if (wv == 0){ Dcol = diagT[lane]; vcur = vwords[0]; }
    for (int g = 0; g < 24; g++){
        if (wv == 0){
            unsigned long long Dnext = (g < 23) ? diagT[(g+1)*64 + lane] : 0ull;
            unsigned long long vnext = (g < 23) ? vwords[g+1] : 0ull;
            bool s = (((vcur >> lane) & 1ull) != 0ull) && (((SS >> g) & 1u) == 0u);
            unsigned long long W = __ballot(s);
            unsigned long long keptW = 0ull, pending = W;
            while (pending){
                int i = __ffsll((long long)pending) - 1;
                keptW |= 1ull << i;
                s = s && (((Dcol >> i) & 1ull) == 0ull);
                W = __ballot(s);
                unsigned long long above = (i == 63) ? 0ull : (~0ull << (i+1));
                pending = W & above;
            }
            if (lane == 0) keepw[g] = keptW;
            Dcol = Dnext; vcur = vnext;
        }
        __syncthreads();                      // keepw[g] visible to all waves
        unsigned long long keptW = keepw[g];
        unsigned kbits = (unsigned)((keptW >> (wv*16)) & 0xFFFFull);   // wave-uniform
        const unsigned* base = Tcol + (size_t)(g*64 + wv*16)*64 + lane;
        unsigned a0=0u, a1=0u, a2=0u, a3=0u;
        #pragma unroll
        for (int i=0; i<4; i++){
            unsigned r0 = base[(i*4+0)*64];
            unsigned r1 = base[(i*4+1)*64];
            unsigned r2 = base[(i*4+2)*64];
            unsigned r3 = base[(i*4+3)*64];
            a0 |= (0u - ((kbits >> (i*4+0)) & 1u)) & r0;
            a1 |= (0u - ((kbits >> (i*4+1)) & 1u)) & r1;
            a2 |= (0u - ((kbits >> (i*4+2)) & 1u)) & r2;
            a3 |= (0u - ((kbits >> (i*4+3)) & 1u)) & r3;
        }
        partial[wv][lane] = (a0 | a1) | (a2 | a3);
        __syncthreads();                      // partials visible
        if (wv == 0)
            SS |= partial[0][lane] | partial[1][lane] | partial[2][lane] | partial[3][lane];
    }
    for (int e=t; e<NBOX*9; e+=256){
        int r = e / 9;
        int c = e - r*9;
        bool kp = ((keepw[r >> 6] >> (r & 63)) & 1ull) != 0ull;
        out[e] = kp ? sboxes[r*12 + c] : 0.f;
    }
}

extern "C" void kernel_launch(void* const* d_in, const int* in_sizes, int n_in,
                              void* d_out, int out_size, void* d_ws, size_t ws_size,
                              hipStream_t stream){
    const float* o13 = (const float*)d_in[0];
    const float* o26 = (const float*)d_in[1];
    const float* o52 = (const float*)d_in[2];
    const float* a13 = (const float*)d_in[3];
    const float* a26 = (const float*)d_in[4];
    const float* a52 = (const float*)d_in[5];
    char* ws = (char*)d_ws;
    unsigned long long* cand  = (unsigned long long*)(ws);              // TOTCELL*8 = 2,725,632
    unsigned* Tcol            = (unsigned*)(ws);                        // 393,216 — ALIASES cand (cand dead after k_classify)
    int* hist                 = (int*)(ws + 2752512);                   // 12,288
    int* cnt                  = (int*)(ws + 2801664);                   // 256
    unsigned long long* sel   = (unsigned long long*)(ws + 2801920);    // 12,288
    unsigned long long* stash = (unsigned long long*)(ws + 2814208);    // 24,576
    float* boxes              = (float*)(ws + 2838784);                 // 73,728
    float* sboxes             = (float*)(ws + 2912512);                 // 73,728
    unsigned long long* vw    = (unsigned long long*)(ws + 2986240);    // 256
    unsigned long long* diagT = (unsigned long long*)(ws + 2986496);    // 12,288 (end ~3.0 MB)
    float* out = (float*)d_out;

    k_init    <<<48, 256, 0, stream>>>(hist, cnt, diagT);
    k_score   <<<(TOTCELL + 255)/256, 256, 0, stream>>>(o13, o26, o52, cand, hist);
    k_cutoff  <<<3, NBINS, 0, stream>>>(hist, cnt);
    k_classify<<<(TOTCELL + 255)/256, 256, 0, stream>>>(cand, cnt, sel, stash);
    k_finalize<<<3, 1024, 0, stream>>>(cnt, sel, stash);
    k_decode  <<<NBOX/4, 256, 0, stream>>>(o13, o26, o52, a13, a26, a52, sel, boxes);
    k_sort    <<<1, 1024, 0, stream>>>(sel, boxes, sboxes, vw);
    k_masks   <<<NBOX, 64, 0, stream>>>(sboxes, Tcol, diagT);
    k_nms_out <<<1, 256, 0, stream>>>(sboxes, vw, diagT, Tcol, out);
}

// Round 7
// 303.525 us; speedup vs baseline: 1.6446x; 1.0198x over previous
//
#include <hip/hip_runtime.h>
#include <stdint.h>

#define KPS 512
#define NBOX 1536
#define NBINS 1024

// scale cell counts: 32*H*H*3
#define S13 16224
#define S26 64896
#define S52 259584
#define TOTCELL 340704

__device__ __forceinline__ uint32_t f2u(float x){ union{float f;uint32_t u;}v; v.f=x; return v.u; }
__device__ __forceinline__ float u2f(uint32_t x){ union{float f;uint32_t u;}v; v.u=x; return v.f; }

__device__ __forceinline__ int binOf(float s){
    int b = (int)((s - 0.6f) * 2560.0f);    // 1024 bins over (0.6, 1.0)
    if (b < 0) b = 0;
    if (b > NBINS-1) b = NBINS-1;
    return b;
}

// counters: [3..5] abovePos, [6..8] stashCnt, [9..11] cutoffB, [12..14] aboveCount
__global__ void k_init(int* hist, int* cnt, unsigned long long* diagT){
    int id = blockIdx.x*256 + threadIdx.x;
    if (id < 3*NBINS) hist[id] = 0;
    if (id < 32) cnt[id] = 0;
    if (id < NBOX) diagT[id] = 0ull;
}

// Sparse candidate slots: cand[id] = key or 0. No wave-stalling atomics.
__global__ void k_score(const float* __restrict__ o13, const float* __restrict__ o26,
                        const float* __restrict__ o52,
                        unsigned long long* __restrict__ cand, int* __restrict__ hist){
    int id = blockIdx.x*256 + threadIdx.x;
    if (id >= TOTCELL) return;
    int scale, idl, H;
    const float* src;
    if (id < S13)            { scale=0; idl=id;            H=13; src=o13; }
    else if (id < S13+S26)   { scale=1; idl=id-S13;        H=26; src=o26; }
    else                     { scale=2; idl=id-(S13+S26);  H=52; src=o52; }
    int HW = H*H;
    // plane-major thread mapping for coalescing: idl = p*HW + hw, p = n*3 + a
    int p  = idl / HW;
    int hw = idl - p*HW;
    int n  = p / 3;
    int a  = p - n*3;
    int cidx = (n*HW + hw)*3 + a;       // reference flat cell index
    float x = src[(size_t)(n*255 + a*85)*HW + hw];
    float s = (float)(1.0 / (1.0 + exp(-(double)x)));   // correctly-rounded f32 sigmoid
    unsigned long long key = 0ull;
    if (s > 0.6f){
        key = ((unsigned long long)f2u(s) << 20)
            | ((unsigned long long)(2-scale) << 18)
            | (unsigned long long)(262143 - cidx);
        atomicAdd(&hist[scale*NBINS + binOf(s)], 1);   // fire-and-forget, spread bins
    }
    cand[id] = key;
}

__global__ void __launch_bounds__(1024) k_cutoff(const int* __restrict__ hist, int* __restrict__ cnt){
    int s = blockIdx.x, t = threadIdx.x;
    __shared__ int suf[NBINS];
    int h = hist[s*NBINS + t];
    suf[t] = h; __syncthreads();
    for (int d=1; d<NBINS; d<<=1){
        int v = (t+d < NBINS) ? suf[t+d] : 0;
        __syncthreads();
        suf[t] += v;
        __syncthreads();
    }
    int total = suf[0];
    int A = (t < NBINS-1) ? suf[t+1] : 0;   // count strictly above bin t
    if (t == 0 && total < KPS){ cnt[9+s] = -1; cnt[12+s] = total; }
    if (A < KPS && A + h >= KPS){ cnt[9+s] = t; cnt[12+s] = A; }
}

__global__ void k_classify(const unsigned long long* __restrict__ cand, int* __restrict__ cnt,
                           unsigned long long* __restrict__ sel, unsigned long long* __restrict__ stash){
    int id = blockIdx.x*256 + threadIdx.x;
    unsigned long long key = (id < TOTCELL) ? cand[id] : 0ull;
    bool live = (key != 0ull);
    int scale = live ? (2 - (int)((key >> 18) & 3ull)) : 0;
    int bin = live ? binOf(u2f((uint32_t)(key >> 20))) : -2;
    int B = cnt[9+scale];
    int lane = threadIdx.x & 63;
    unsigned long long lanebit_m1 = (lane == 63) ? ~0ull >> 1 : ((1ull << lane) - 1ull);
    bool above = live && (bin > B);
    bool bound = live && (bin == B);
    // wave-aggregate both counters (waves may straddle scales; loop scales)
    #pragma unroll
    for (int sc = 0; sc < 3; sc++){
        unsigned long long ma = __ballot(above && scale == sc);
        if (ma){
            int leader = __ffsll((long long)ma) - 1;
            int base = 0;
            if (lane == leader) base = atomicAdd(&cnt[3+sc], __popcll(ma));
            base = __shfl(base, leader);
            if (above && scale == sc)
                sel[sc*KPS + base + __popcll(ma & lanebit_m1)] = key;
        }
        unsigned long long mb = __ballot(bound && scale == sc);
        if (mb){
            int leader = __ffsll((long long)mb) - 1;
            int base = 0;
            if (lane == leader) base = atomicAdd(&cnt[6+sc], __popcll(mb));
            base = __shfl(base, leader);
            if (bound && scale == sc){
                int q = base + __popcll(mb & lanebit_m1);
                if (q < 1024) stash[sc*1024 + q] = key;
            }
        }
    }
}

__global__ void __launch_bounds__(1024) k_finalize(const int* __restrict__ cnt,
                           unsigned long long* __restrict__ sel, const unsigned long long* __restrict__ stash){
    int s = blockIdx.x, t = threadIdx.x;
    __shared__ unsigned long long sk[1024];
    int sc = cnt[6+s]; if (sc > 1024) sc = 1024;
    sk[t] = (t < sc) ? stash[s*1024 + t] : 0ull;
    __syncthreads();
    for (int k=2; k<=1024; k<<=1)
        for (int j=k>>1; j>0; j>>=1){
            int ixj = t ^ j;
            if (ixj > t){
                bool up = ((t & k) == 0);   // descending overall
                unsigned long long a = sk[t], b = sk[ixj];
                if (up ? (a < b) : (a > b)){ sk[t] = b; sk[ixj] = a; }
            }
            __syncthreads();
        }
    int above = cnt[12+s];
    int need = KPS - above; if (need < 0) need = 0;
    int m = (need < sc) ? need : sc;
    if (t < m) sel[s*KPS + above + t] = sk[t];
    if (t >= above + m && t < KPS) sel[s*KPS + t] = 0ull;   // sentinels
}

__global__ void k_decode(const float* __restrict__ o13, const float* __restrict__ o26,
                         const float* __restrict__ o52,
                         const float* __restrict__ a13, const float* __restrict__ a26,
                         const float* __restrict__ a52,
                         const unsigned long long* __restrict__ sel, float* __restrict__ boxes){
    int gtid = blockIdx.x*256 + threadIdx.x;
    int b = gtid >> 6;
    int lane = threadIdx.x & 63;
    if (b >= NBOX) return;
    unsigned long long key = sel[b];
    float* row = boxes + b*12;
    if ((key >> 20) == 0ull){           // sentinel
        if (lane < 9) row[lane] = 0.f;
        return;
    }
    int scale = 2 - (int)((key >> 18) & 3ull);
    int cidx  = 262143 - (int)(key & 0x3FFFFull);
    uint32_t sbits = (uint32_t)(key >> 20);
    const float* src; const float* anch; int H; float tt;
    if (scale == 0){ src=o13; anch=a13; H=13; tt=32.f; }
    else if (scale == 1){ src=o26; anch=a26; H=26; tt=16.f; }
    else { src=o52; anch=a52; H=52; tt=8.f; }
    int HW = H*H;
    int a  = cidx % 3;
    int hw = (cidx/3) % HW;
    int n  = cidx / (3*HW);
    int hh = hw / H;
    int ww = hw - hh*H;
    const float* cellbase = src + (size_t)(n*255 + a*85)*HW + hw;
    // argmax over 80 classes, tie -> lowest class index
    float bv = cellbase[(size_t)(5 + lane)*HW];
    int bi = lane;
    if (lane < 16){
        float v2 = cellbase[(size_t)(69 + lane)*HW];
        if (v2 > bv){ bv = v2; bi = 64 + lane; }
    }
    #pragma unroll
    for (int off=32; off; off>>=1){
        float vo = __shfl_xor(bv, off);
        int io = __shfl_xor(bi, off);
        if (vo > bv || (vo == bv && io < bi)){ bv = vo; bi = io; }
    }
    if (lane == 0){
        float v1 = cellbase[(size_t)1*HW];
        float v2 = cellbase[(size_t)2*HW];
        float v3 = cellbase[(size_t)3*HW];
        float v4 = cellbase[(size_t)4*HW];
        float cx = ((float)ww + v1) * tt / 416.0f;
        float cy = ((float)hh + v2) * tt / 416.0f;
        float e3 = (float)exp((double)v3);
        float e4 = (float)exp((double)v4);
        float bw = anch[a*2+0] * e3 / 416.0f;
        float bh = anch[a*2+1] * e4 / 416.0f;
        row[0] = (float)n;  row[1] = cx; row[2] = cy; row[3] = bw; row[4] = bh;
        row[5] = u2f(sbits); row[6] = (float)bi; row[7] = (float)hh; row[8] = (float)ww;
    }
}

__global__ void __launch_bounds__(1024) k_sort(const unsigned long long* __restrict__ sel,
                       const float* __restrict__ boxes, float* __restrict__ sboxes,
                       unsigned long long* __restrict__ vwords){
    __shared__ unsigned long long sk[2048];
    int t = threadIdx.x;
    for (int r=t; r<2048; r+=1024)
        sk[r] = (r < NBOX) ? ((sel[r] << 12) | (unsigned long long)r) : 0ull;
    __syncthreads();
    for (int k=2; k<=2048; k<<=1)
        for (int j=k>>1; j>0; j>>=1){
            for (int i=t; i<2048; i+=1024){
                int ixj = i ^ j;
                if (ixj > i){
                    bool up = ((i & k) == 0);
                    unsigned long long a = sk[i], b = sk[ixj];
                    if (up ? (a < b) : (a > b)){ sk[i] = b; sk[ixj] = a; }
                }
            }
            __syncthreads();
        }
    for (int r=t; r<2048; r+=1024){
        if (r < NBOX){
            unsigned long long key = sk[r];
            bool valid = (key >> 32) != 0ull;     // top 32 bits = sigmoid bits
            int slot = (int)(key & 0xFFFull);
            #pragma unroll
            for (int c=0;c<9;c++) sboxes[r*12+c] = valid ? boxes[slot*12+c] : 0.f;
            unsigned long long ball = __ballot(valid);
            if ((r & 63) == 0) vwords[r >> 6] = ball;
        }
    }
}

// Column-sliced suppression matrix: Tcol[i*64 + j] bit c = sup(i, c*64+j).
// Diagonal-tile transpose: diagT[g*64 + j] bit i = sup(g*64+i, g*64+j).
__global__ void k_masks(const float* __restrict__ sboxes, unsigned* __restrict__ Tcol,
                        unsigned long long* __restrict__ diagT){
    int i = blockIdx.x;
    int lane = threadIdx.x;
    int gi = i >> 6, ii = i & 63;
    float cxi = sboxes[i*12+1], cyi = sboxes[i*12+2], wi = sboxes[i*12+3], hi = sboxes[i*12+4];
    float x1i = cxi - wi/2.0f, y1i = cyi - hi/2.0f, x2i = cxi + wi/2.0f, y2i = cyi + hi/2.0f;
    float ari = fmaxf(x2i-x1i, 0.f) * fmaxf(y2i-y1i, 0.f);
    unsigned colbits = 0u;
    for (int c=0; c<24; c++){
        int j = c*64 + lane;
        float cxj = sboxes[j*12+1], cyj = sboxes[j*12+2], wj = sboxes[j*12+3], hj = sboxes[j*12+4];
        float x1j = cxj - wj/2.0f, y1j = cyj - hj/2.0f, x2j = cxj + wj/2.0f, y2j = cyj + hj/2.0f;
        float arj = fmaxf(x2j-x1j, 0.f) * fmaxf(y2j-y1j, 0.f);
        float ix = fmaxf(0.f, fminf(x2i, x2j) - fmaxf(x1i, x1j));
        float iy = fmaxf(0.f, fminf(y2i, y2j) - fmaxf(y1i, y1j));
        float inter = ix * iy;
        float iou = inter / fmaxf(fminf(ari, arj), 1e-9f);
        bool sb = (iou > 0.7f) && (j > i);
        colbits |= sb ? (1u << c) : 0u;
    }
    Tcol[(size_t)i*64 + lane] = colbits;
    if ((colbits >> gi) & 1u)
        atomicOr(&diagT[gi*64 + lane], 1ull << ii);
}

// Greedy NMS scan, fully pipelined:
//  - ALL 4 waves run the resolve chain redundantly (identical per-lane state =>
//    identical ballots), so no keepw broadcast barrier and no idle waves.
//  - Tcol row loads for tile g+1 are unconditional and issued while tile g is
//    merged + tile g+1 resolved (LLC latency hidden).
//  - partial[] double-buffered => ONE barrier per tile.
__global__ void k_nms_out(const float* __restrict__ sboxes, const unsigned long long* __restrict__ vwords,
                          const unsigned long long* __restrict__ diagT, const unsigned* __restrict__ Tcol,
                          float* __restrict__ out){
    __shared__ unsigned long long keepw[24];
    __shared__ unsigned partial[2][4][64];
    int t = threadIdx.x;
    int wv = t >> 6, lane = t & 63;
    unsigned SS = 0u;      // bit g = box g*64+lane suppressed; identical in all waves
    unsigned long long Dcol = diagT[lane];
    unsigned long long vcur = vwords[0];
    unsigned rows[16];
    {
        const unsigned* b0 = Tcol + (size_t)(wv*16)*64 + lane;
        #pragma unroll
        for (int i=0;i<16;i++) rows[i] = b0[i*64];
    }
    for (int g = 0; g < 24; g++){
        // resolve tile g (redundant in every wave)
        bool s = (((vcur >> lane) & 1ull) != 0ull) && (((SS >> g) & 1u) == 0u);
        unsigned long long W = __ballot(s);
        unsigned long long keptW = 0ull, pending = W;
        while (pending){
            int i = __ffsll((long long)pending) - 1;
            keptW |= 1ull << i;
            s = s && (((Dcol >> i) & 1ull) == 0ull);
            W = __ballot(s);
            unsigned long long above = (i == 63) ? 0ull : (~0ull << (i+1));
            pending = W & above;
        }
        if (t == 0) keepw[g] = keptW;
        // prefetch next tile's diag/valid (consumed next resolve)
        unsigned long long Dnext = (g < 23) ? diagT[(g+1)*64 + lane] : 0ull;
        unsigned long long vnext = (g < 23) ? vwords[g+1] : 0ull;
        // mask current rows by kept bits, reduce to this wave's partial
        unsigned kbits = (unsigned)((keptW >> (wv*16)) & 0xFFFFull);   // wave-uniform
        unsigned acc = 0u;
        #pragma unroll
        for (int i=0;i<16;i++) acc |= (0u - ((kbits >> i) & 1u)) & rows[i];
        // issue next tile's row loads now (in flight across barrier+merge+resolve)
        if (g < 23){
            const unsigned* nb = Tcol + (size_t)((g+1)*64 + wv*16)*64 + lane;
            #pragma unroll
            for (int i=0;i<16;i++) rows[i] = nb[i*64];
        }
        partial[g & 1][wv][lane] = acc;
        __syncthreads();
        SS |= partial[g & 1][0][lane] | partial[g & 1][1][lane]
            | partial[g & 1][2][lane] | partial[g & 1][3][lane];
        Dcol = Dnext; vcur = vnext;
    }
    for (int e=t; e<NBOX*9; e+=256){
        int r = e / 9;
        int c = e - r*9;
        bool kp = ((keepw[r >> 6] >> (r & 63)) & 1ull) != 0ull;
        out[e] = kp ? sboxes[r*12 + c] : 0.f;
    }
}

extern "C" void kernel_launch(void* const* d_in, const int* in_sizes, int n_in,
                              void* d_out, int out_size, void* d_ws, size_t ws_size,
                              hipStream_t stream){
    const float* o13 = (const float*)d_in[0];
    const float* o26 = (const float*)d_in[1];
    const float* o52 = (const float*)d_in[2];
    const float* a13 = (const float*)d_in[3];
    const float* a26 = (const float*)d_in[4];
    const float* a52 = (const float*)d_in[5];
    char* ws = (char*)d_ws;
    unsigned long long* cand  = (unsigned long long*)(ws);              // TOTCELL*8 = 2,725,632
    unsigned* Tcol            = (unsigned*)(ws);                        // 393,216 — ALIASES cand (cand dead after k_classify)
    int* hist                 = (int*)(ws + 2752512);                   // 12,288
    int* cnt                  = (int*)(ws + 2801664);                   // 256
    unsigned long long* sel   = (unsigned long long*)(ws + 2801920);    // 12,288
    unsigned long long* stash = (unsigned long long*)(ws + 2814208);    // 24,576
    float* boxes              = (float*)(ws + 2838784);                 // 73,728
    float* sboxes             = (float*)(ws + 2912512);                 // 73,728
    unsigned long long* vw    = (unsigned long long*)(ws + 2986240);    // 256
    unsigned long long* diagT = (unsigned long long*)(ws + 2986496);    // 12,288 (end ~3.0 MB)
    float* out = (float*)d_out;

    k_init    <<<48, 256, 0, stream>>>(hist, cnt, diagT);
    k_score   <<<(TOTCELL + 255)/256, 256, 0, stream>>>(o13, o26, o52, cand, hist);
    k_cutoff  <<<3, NBINS, 0, stream>>>(hist, cnt);
    k_classify<<<(TOTCELL + 255)/256, 256, 0, stream>>>(cand, cnt, sel, stash);
    k_finalize<<<3, 1024, 0, stream>>>(cnt, sel, stash);
    k_decode  <<<NBOX/4, 256, 0, stream>>>(o13, o26, o52, a13, a26, a52, sel, boxes);
    k_sort    <<<1, 1024, 0, stream>>>(sel, boxes, sboxes, vw);
    k_masks   <<<NBOX, 64, 0, stream>>>(sboxes, Tcol, diagT);
    k_nms_out <<<1, 256, 0, stream>>>(sboxes, vw, diagT, Tcol, out);
}